// Round 1
// baseline (11523.431 us; speedup 1.0000x reference)
//
#include <hip/hip_runtime.h>

#define CIN 32
#define COUT 32
#define LRELU_SLOPE 0.01f
#define BN_EPS 1e-5f

__global__ void __launch_bounds__(256) conv_kernel(
    const float* __restrict__ features,
    const float* __restrict__ weight,
    const int* __restrict__ pairs_in,
    const int* __restrict__ pairs_out,
    float* __restrict__ out,
    int P)
{
    int p = blockIdx.x * blockDim.x + threadIdx.x;
    int k = blockIdx.y;                 // wave-uniform -> W accesses become s_load
    if (p >= P) return;

    int pi = pairs_in[(size_t)k * P + p];
    int po = pairs_out[(size_t)k * P + p];

    const float4* __restrict__ frow = (const float4*)(features + (size_t)pi * CIN);
    const float* __restrict__ wk = weight + (size_t)k * CIN * COUT;

    float acc[COUT];
#pragma unroll
    for (int co = 0; co < COUT; ++co) acc[co] = 0.f;

#pragma unroll
    for (int c4 = 0; c4 < CIN / 4; ++c4) {
        float4 f = frow[c4];
        float fv[4] = {f.x, f.y, f.z, f.w};
#pragma unroll
        for (int j = 0; j < 4; ++j) {
            const float* __restrict__ wr = wk + (c4 * 4 + j) * COUT;
#pragma unroll
            for (int co = 0; co < COUT; ++co)
                acc[co] = fmaf(fv[j], wr[co], acc[co]);
        }
    }

    float* orow = out + (size_t)po * COUT;
#pragma unroll
    for (int co = 0; co < COUT; ++co)
        atomicAdd(orow + co, acc[co]);
}

__device__ __forceinline__ float4 lrelu4(float4 v) {
    float4 a;
    a.x = v.x >= 0.f ? v.x : LRELU_SLOPE * v.x;
    a.y = v.y >= 0.f ? v.y : LRELU_SLOPE * v.y;
    a.z = v.z >= 0.f ? v.z : LRELU_SLOPE * v.z;
    a.w = v.w >= 0.f ? v.w : LRELU_SLOPE * v.w;
    return a;
}

// ws[0..31]  = sum(act)   per channel
// ws[32..63] = sum(act^2) per channel
__global__ void __launch_bounds__(256) stats_kernel(
    const float* __restrict__ conv, float* __restrict__ ws, int n4)
{
    const float4* __restrict__ c4p = (const float4*)conv;
    int stride = blockDim.x * gridDim.x;   // multiple of 8
    float4 s = {0.f, 0.f, 0.f, 0.f};
    float4 q = {0.f, 0.f, 0.f, 0.f};
    for (int i = blockIdx.x * blockDim.x + threadIdx.x; i < n4; i += stride) {
        float4 a = lrelu4(c4p[i]);
        s.x += a.x; s.y += a.y; s.z += a.z; s.w += a.w;
        q.x += a.x * a.x; q.y += a.y * a.y; q.z += a.z * a.z; q.w += a.w * a.w;
    }
    // wave reduce across lanes with same (lane & 7)
#pragma unroll
    for (int off = 8; off < 64; off <<= 1) {
        s.x += __shfl_xor(s.x, off); s.y += __shfl_xor(s.y, off);
        s.z += __shfl_xor(s.z, off); s.w += __shfl_xor(s.w, off);
        q.x += __shfl_xor(q.x, off); q.y += __shfl_xor(q.y, off);
        q.z += __shfl_xor(q.z, off); q.w += __shfl_xor(q.w, off);
    }
    __shared__ float4 red_s[4][8];
    __shared__ float4 red_q[4][8];
    int lane = threadIdx.x & 63;
    int w = threadIdx.x >> 6;
    if (lane < 8) { red_s[w][lane] = s; red_q[w][lane] = q; }
    __syncthreads();
    if (threadIdx.x < 8) {
        int qd = threadIdx.x;
        float4 S = {0.f, 0.f, 0.f, 0.f};
        float4 Q = {0.f, 0.f, 0.f, 0.f};
        for (int ww = 0; ww < 4; ++ww) {
            float4 a = red_s[ww][qd], b = red_q[ww][qd];
            S.x += a.x; S.y += a.y; S.z += a.z; S.w += a.w;
            Q.x += b.x; Q.y += b.y; Q.z += b.z; Q.w += b.w;
        }
        atomicAdd(&ws[qd * 4 + 0], S.x); atomicAdd(&ws[qd * 4 + 1], S.y);
        atomicAdd(&ws[qd * 4 + 2], S.z); atomicAdd(&ws[qd * 4 + 3], S.w);
        atomicAdd(&ws[32 + qd * 4 + 0], Q.x); atomicAdd(&ws[32 + qd * 4 + 1], Q.y);
        atomicAdd(&ws[32 + qd * 4 + 2], Q.z); atomicAdd(&ws[32 + qd * 4 + 3], Q.w);
    }
}

__global__ void __launch_bounds__(256) norm_kernel(
    float* __restrict__ data, const float* __restrict__ ws,
    const float* __restrict__ gamma, const float* __restrict__ beta,
    int n4, float invN)
{
    int i = blockIdx.x * blockDim.x + threadIdx.x;
    if (i >= n4) return;
    int qd = i & 7;            // channel quad: channels 4*qd .. 4*qd+3
    float sc[4], bs[4];
#pragma unroll
    for (int j = 0; j < 4; ++j) {
        int c = qd * 4 + j;
        float m = ws[c] * invN;
        float v = ws[32 + c] * invN - m * m;
        float inv = rsqrtf(v + BN_EPS);
        sc[j] = inv * gamma[c];
        bs[j] = beta[c] - m * sc[j];
    }
    float4* d4 = (float4*)data;
    float4 a = lrelu4(d4[i]);
    float4 y;
    y.x = a.x * sc[0] + bs[0];
    y.y = a.y * sc[1] + bs[1];
    y.z = a.z * sc[2] + bs[2];
    y.w = a.w * sc[3] + bs[3];
    d4[i] = y;
}

extern "C" void kernel_launch(void* const* d_in, const int* in_sizes, int n_in,
                              void* d_out, int out_size, void* d_ws, size_t ws_size,
                              hipStream_t stream) {
    const float* features = (const float*)d_in[0];
    const float* weight   = (const float*)d_in[1];
    const float* gamma    = (const float*)d_in[2];
    const float* beta     = (const float*)d_in[3];
    const int* pairs_in   = (const int*)d_in[4];
    const int* pairs_out  = (const int*)d_in[5];
    float* out = (float*)d_out;
    float* ws  = (float*)d_ws;

    int N  = in_sizes[0] / CIN;          // 500000
    int KW = in_sizes[1] / (CIN * COUT); // 27
    int P  = in_sizes[4] / KW;           // 250000

    // d_out is poisoned 0xAA -> zero it (it is the conv accumulator)
    hipMemsetAsync(d_out, 0, (size_t)out_size * sizeof(float), stream);
    hipMemsetAsync(d_ws, 0, 64 * sizeof(float), stream);

    dim3 cgrid((P + 255) / 256, KW);
    conv_kernel<<<cgrid, 256, 0, stream>>>(features, weight, pairs_in, pairs_out, out, P);

    int n4 = N * (COUT / 4);             // 4,000,000 float4s
    stats_kernel<<<512, 256, 0, stream>>>(out, ws, n4);
    norm_kernel<<<(n4 + 255) / 256, 256, 0, stream>>>(out, ws, gamma, beta, n4,
                                                      1.0f / (float)N);
}